// Round 4
// baseline (195.504 us; speedup 1.0000x reference)
//
#include <hip/hip_runtime.h>

// BayesTensorRing, direct-compute path: out[s] = trace(M0'·M1'·M2'·M3'),
// Md' = core_d[idx_d]·diag(lam_d), prescaled into d_ws (800 KB, L2-resident).
//
// 4 lanes per sample (lane j owns rows 4j..4j+3 of the running 16x16 product).
// NO LDS: M1'/M2' are read directly from global with 4-lane-broadcast float4
// loads (16 distinct float4 per wave inst, L2-served). R2 was LDS-pipe-bound
// (~120 LDS-cyc/sample vs 66 VALU-cyc); this moves the traffic to the L2 path.

constexpr int SPB = 64;
constexpr int BLK = 256;

#define DEV static __device__ __forceinline__

// b[r][k] = sum_n a[r][n] * m[n*16+k]; m = global ptr to a prescaled 16x16
// slice. All 4 lanes of a group read identical addresses (hardware broadcast).
DEV void mm16g(const float (&a)[4][16], float (&b)[4][16], const float* __restrict__ m)
{
    const float4* m4 = reinterpret_cast<const float4*>(m);
#pragma unroll
    for (int nn = 0; nn < 16; ++nn) {
        float mrow[16];
#pragma unroll
        for (int q = 0; q < 4; ++q) {
            const float4 v = m4[4 * nn + q];
            mrow[4*q+0] = v.x; mrow[4*q+1] = v.y;
            mrow[4*q+2] = v.z; mrow[4*q+3] = v.w;
        }
#pragma unroll
        for (int r = 0; r < 4; ++r) {
            const float av = a[r][nn];
            if (nn == 0) {
#pragma unroll
                for (int k = 0; k < 16; ++k) b[r][k] = av * mrow[k];
            } else {
#pragma unroll
                for (int k = 0; k < 16; ++k) b[r][k] = fmaf(av, mrow[k], b[r][k]);
            }
        }
    }
}

// W = prescaled cores: W0 @ 0, W1 @ 51200, W2 @ 102400, W3 @ 153600 (floats)
__global__ __launch_bounds__(BLK)
void chain_kernel(const int* __restrict__ idx, const float* __restrict__ W,
                  float* __restrict__ out, int n)
{
    const int tid  = threadIdx.x;
    const int slot = tid >> 2;          // sample slot in block, 0..63
    const int j    = tid & 3;           // lane within 4-lane sample group
    const int s    = blockIdx.x * SPB + slot;
    const int sc   = s < n ? s : n - 1; // clamp (keeps loads in-bounds)

    const int4 ix = *reinterpret_cast<const int4*>(idx + 4l * sc);
    const float* m0 = W + 256l * ix.x;
    const float* m1 = W +  51200 + 256l * ix.y;
    const float* m2 = W + 102400 + 256l * ix.z;
    const float* m3 = W + 153600 + 256l * ix.w;

    // ---- a = M0' rows 4j..4j+3 (lane-distinct, coalesced within the group)
    float a[4][16], b[4][16];
    {
        const float4* src = reinterpret_cast<const float4*>(m0) + 16 * j;
#pragma unroll
        for (int t = 0; t < 16; ++t) {
            const float4 v = src[t];
            const int r = t >> 2, c = (t & 3) * 4;
            a[r][c+0] = v.x; a[r][c+1] = v.y; a[r][c+2] = v.z; a[r][c+3] = v.w;
        }
    }

    // ---- b = a @ M1' ; a = b @ M2'   (broadcast global reads, L2-served)
    mm16g(a, b, m1);
    mm16g(b, a, m2);

    // ---- trace with M3': part.r = sum_n a[r][n] * M3'[n][4j+r]
    float4 part = make_float4(0.f, 0.f, 0.f, 0.f);
    const float* base3 = m3 + 4 * j;
#pragma unroll
    for (int nn = 0; nn < 16; ++nn) {
        const float4 v = *reinterpret_cast<const float4*>(base3 + 16 * nn);
        part.x = fmaf(a[0][nn], v.x, part.x);
        part.y = fmaf(a[1][nn], v.y, part.y);
        part.z = fmaf(a[2][nn], v.z, part.z);
        part.w = fmaf(a[3][nn], v.w, part.w);
    }
    float p = part.x + part.y + part.z + part.w;

    // reduce across the 4-lane group
    p += __shfl_xor(p, 1);
    p += __shfl_xor(p, 2);

    if (s < n && j == 0) out[s] = p;
}

// ws[d][i][r][c] = core_d[i][r][c] * lam_d[c]; 4 x 200 x 16 x 16 floats = 819,200 B
__global__ __launch_bounds__(256)
void scale_cores_kernel(const float* __restrict__ c0, const float* __restrict__ l0,
                        const float* __restrict__ c1, const float* __restrict__ l1,
                        const float* __restrict__ c2, const float* __restrict__ l2,
                        const float* __restrict__ c3, const float* __restrict__ l3,
                        float* __restrict__ ws)
{
    const int gid = blockIdx.x * 256 + threadIdx.x;   // float4 id, 0..51199
    const int d   = gid / 12800;                      // uniform per block (12800 % 256 == 0)
    const int w   = gid - d * 12800;
    const float* cs[4] = {c0, c1, c2, c3};
    const float* ls[4] = {l0, l1, l2, l3};
    const float4 v = reinterpret_cast<const float4*>(cs[d])[w];
    const float4 L = reinterpret_cast<const float4*>(ls[d])[w & 3];
    float4 o;
    o.x = v.x * L.x; o.y = v.y * L.y; o.z = v.z * L.z; o.w = v.w * L.w;
    reinterpret_cast<float4*>(ws)[d * 12800 + w] = o;
}

// ---------------- fallback (lambda applied inline, no workspace) ----------------
DEV void mm16g_lam(const float (&a)[4][16], float (&b)[4][16],
                   const float* __restrict__ m, const float* __restrict__ lam)
{
    const float4* m4 = reinterpret_cast<const float4*>(m);
    float4 lv[4];
#pragma unroll
    for (int q = 0; q < 4; ++q) lv[q] = reinterpret_cast<const float4*>(lam)[q];
#pragma unroll
    for (int nn = 0; nn < 16; ++nn) {
        float mrow[16];
#pragma unroll
        for (int q = 0; q < 4; ++q) {
            float4 v = m4[4 * nn + q];
            v.x *= lv[q].x; v.y *= lv[q].y; v.z *= lv[q].z; v.w *= lv[q].w;
            mrow[4*q+0] = v.x; mrow[4*q+1] = v.y;
            mrow[4*q+2] = v.z; mrow[4*q+3] = v.w;
        }
#pragma unroll
        for (int r = 0; r < 4; ++r) {
            const float av = a[r][nn];
            if (nn == 0) {
#pragma unroll
                for (int k = 0; k < 16; ++k) b[r][k] = av * mrow[k];
            } else {
#pragma unroll
                for (int k = 0; k < 16; ++k) b[r][k] = fmaf(av, mrow[k], b[r][k]);
            }
        }
    }
}

__global__ __launch_bounds__(BLK)
void chain_kernel_fb(const int* __restrict__ idx,
                     const float* __restrict__ c0, const float* __restrict__ l0,
                     const float* __restrict__ c1, const float* __restrict__ l1,
                     const float* __restrict__ c2, const float* __restrict__ l2,
                     const float* __restrict__ c3, const float* __restrict__ l3,
                     float* __restrict__ out, int n)
{
    const int tid  = threadIdx.x;
    const int slot = tid >> 2;
    const int j    = tid & 3;
    const int s    = blockIdx.x * SPB + slot;
    const int sc   = s < n ? s : n - 1;

    const int4 ix = *reinterpret_cast<const int4*>(idx + 4l * sc);

    float a[4][16], b[4][16];
    {
        const float4* src = reinterpret_cast<const float4*>(c0 + 256l * ix.x) + 16 * j;
#pragma unroll
        for (int t = 0; t < 16; ++t) {
            float4 v = src[t];
            const float4 L = reinterpret_cast<const float4*>(l0)[t & 3];
            const int r = t >> 2, c = (t & 3) * 4;
            a[r][c+0] = v.x * L.x; a[r][c+1] = v.y * L.y;
            a[r][c+2] = v.z * L.z; a[r][c+3] = v.w * L.w;
        }
    }

    mm16g_lam(a, b, c1 + 256l * ix.y, l1);
    mm16g_lam(b, a, c2 + 256l * ix.z, l2);

    float4 part = make_float4(0.f, 0.f, 0.f, 0.f);
    const float* base3 = c3 + 256l * ix.w + 4 * j;
#pragma unroll
    for (int nn = 0; nn < 16; ++nn) {
        const float4 v = *reinterpret_cast<const float4*>(base3 + 16 * nn);
        part.x = fmaf(a[0][nn], v.x, part.x);
        part.y = fmaf(a[1][nn], v.y, part.y);
        part.z = fmaf(a[2][nn], v.z, part.z);
        part.w = fmaf(a[3][nn], v.w, part.w);
    }
    const float4 L3 = reinterpret_cast<const float4*>(l3)[j];
    float p = part.x * L3.x + part.y * L3.y + part.z * L3.z + part.w * L3.w;

    p += __shfl_xor(p, 1);
    p += __shfl_xor(p, 2);

    if (s < n && j == 0) out[s] = p;
}

extern "C" void kernel_launch(void* const* d_in, const int* in_sizes, int n_in,
                              void* d_out, int out_size, void* d_ws, size_t ws_size,
                              hipStream_t stream)
{
    const int*   idx = (const int*)  d_in[0];
    const float* c0  = (const float*)d_in[1];
    const float* l0  = (const float*)d_in[2];
    const float* c1  = (const float*)d_in[3];
    const float* l1  = (const float*)d_in[4];
    const float* c2  = (const float*)d_in[5];
    const float* l2  = (const float*)d_in[6];
    const float* c3  = (const float*)d_in[7];
    const float* l3  = (const float*)d_in[8];
    float* out = (float*)d_out;

    const int n    = out_size;                 // 500000
    const int grid = (n + SPB - 1) / SPB;      // 7813 blocks

    const size_t need = 4ull * 200 * 256 * sizeof(float);  // 819,200 B
    if (ws_size >= need) {
        float* W = (float*)d_ws;
        hipLaunchKernelGGL(scale_cores_kernel, dim3(200), dim3(256), 0, stream,
                           c0, l0, c1, l1, c2, l2, c3, l3, W);
        hipLaunchKernelGGL(chain_kernel, dim3(grid), dim3(BLK), 0, stream,
                           idx, W, out, n);
    } else {
        hipLaunchKernelGGL(chain_kernel_fb, dim3(grid), dim3(BLK), 0, stream,
                           idx, c0, l0, c1, l1, c2, l2, c3, l3, out, n);
    }
}

// Round 5
// 163.531 us; speedup vs baseline: 1.1955x; 1.1955x over previous
//
#include <hip/hip_runtime.h>

// BayesTensorRing: out[s] = trace(M0'·M1'·M2'·M3'), Md' = core_d[idx_d]·diag(lam_d)
// (prescaled into d_ws, 800 KB, L2-resident). ranks 16, dims 200, N = 500000.
//
// 4 lanes/sample. Lane j holds ROW-slab (rows 4j..4j+3) of the running product.
// Matmul b = a·M: lane j loads COLUMN-block j of M (coalesced 64B per group per
// inst); step T broadcasts lane T's column-block to the quad via DPP quad_perm
// (pure VALU) and computes b columns 4T..4T+3. No LDS, no barriers; all loads
// for a matrix are batched -> one vmcnt wait per ~2500-cycle compute phase.

constexpr int SPB = 64;
constexpr int BLK = 256;

#define DEV static __device__ __forceinline__

template<int CTRL>
DEV float dppf(float x)
{
    return __int_as_float(__builtin_amdgcn_update_dpp(
        0, __float_as_int(x), CTRL, 0xF, 0xF, true));
}

DEV float getc(const float4& v, int c)
{
    switch (c) { case 0: return v.x; case 1: return v.y; case 2: return v.z; default: return v.w; }
}

// Step T of b = a·M: bc = (column-block T of M, broadcast from quad lane T);
// accumulate B[4r+T] (cols 4T..4T+3) over all 16 n. A-slab: A[4r+q].comp(c2)
// = a[row r][col 4q+c2]. All indices compile-time after unroll.
template<int T>
DEV void mm_step(const float4 (&A)[16], float4 (&B)[16], const float4 (&mc)[16])
{
#pragma unroll
    for (int q = 0; q < 4; ++q) {
#pragma unroll
        for (int c2 = 0; c2 < 4; ++c2) {
            const int u = 4 * q + c2;          // n index
            float4 bc;
            bc.x = dppf<T * 0x55>(mc[u].x);
            bc.y = dppf<T * 0x55>(mc[u].y);
            bc.z = dppf<T * 0x55>(mc[u].z);
            bc.w = dppf<T * 0x55>(mc[u].w);
#pragma unroll
            for (int r = 0; r < 4; ++r) {
                const float av = getc(A[4 * r + q], c2);
                float4& o = B[4 * r + T];
                if (u == 0) {
                    o.x = av * bc.x; o.y = av * bc.y;
                    o.z = av * bc.z; o.w = av * bc.w;
                } else {
                    o.x = fmaf(av, bc.x, o.x); o.y = fmaf(av, bc.y, o.y);
                    o.z = fmaf(av, bc.z, o.z); o.w = fmaf(av, bc.w, o.w);
                }
            }
        }
    }
}

// B = A · M ; m4 = matrix base (64 float4, row-major). Lane j loads col-block j.
DEV void mm16s(const float4 (&A)[16], float4 (&B)[16],
               const float4* __restrict__ m4, int j)
{
    float4 mc[16];
#pragma unroll
    for (int u = 0; u < 16; ++u) mc[u] = m4[4 * u + j];   // coalesced 64B/group
    mm_step<0>(A, B, mc);
    mm_step<1>(A, B, mc);
    mm_step<2>(A, B, mc);
    mm_step<3>(A, B, mc);
}

// W = prescaled cores: slice i of mode d at W4 + d*12800 + 64*i (float4 units)
__global__ __launch_bounds__(BLK, 2)
void chain_kernel(const int* __restrict__ idx, const float* __restrict__ W,
                  float* __restrict__ out, int n)
{
    const int tid  = threadIdx.x;
    const int slot = tid >> 2;
    const int j    = tid & 3;
    const int s    = blockIdx.x * SPB + slot;
    const int sc   = s < n ? s : n - 1;

    const int4 ix = *reinterpret_cast<const int4*>(idx + 4l * sc);
    const float4* W4 = reinterpret_cast<const float4*>(W);
    const float4* m0 = W4 +           64l * ix.x;
    const float4* m1 = W4 + 12800 +   64l * ix.y;
    const float4* m2 = W4 + 25600 +   64l * ix.z;
    const float4* m3 = W4 + 38400 +   64l * ix.w;

    // A = M0' row-slab: A[u] = float4 #(16j+u)  (row 4j+(u>>2), colblock u&3)
    // Stored as slab[4r+q] = row r, cols 4q..4q+3  -> A[u]: r=u>>2, q=u&3 -> index 4*(u>>2)+(u&3)
    float4 A[16], B[16];
#pragma unroll
    for (int u = 0; u < 16; ++u)
        A[4 * (u >> 2) + (u & 3)] = m0[16 * j + u];

    mm16s(A, B, m1, j);    // B = M0'·M1'
    mm16s(B, A, m2, j);    // A = (M0'·M1')·M2'

    // trace: lane j owns X rows 4j+lr; needs M3 cols 4j+lr = col-block j, comp lr
    float4 mc3[16];
#pragma unroll
    for (int u = 0; u < 16; ++u) mc3[u] = m3[4 * u + j];  // coalesced

    float p = 0.f;
#pragma unroll
    for (int lr = 0; lr < 4; ++lr) {
#pragma unroll
        for (int q = 0; q < 4; ++q) {
#pragma unroll
            for (int c2 = 0; c2 < 4; ++c2) {
                const int nn = 4 * q + c2;                 // column of X / row of M3
                p = fmaf(getc(A[4 * lr + q], c2), getc(mc3[nn], lr), p);
            }
        }
    }

    // quad butterfly reduce via DPP (xor1 = perm[1,0,3,2]=0xB1, xor2 = perm[2,3,0,1]=0x4E)
    p += dppf<0xB1>(p);
    p += dppf<0x4E>(p);

    if (s < n && j == 0) out[s] = p;
}

// ws[d][i][r][c] = core_d[i][r][c] * lam_d[c]; 4 x 200 x 256 floats = 819,200 B
__global__ __launch_bounds__(256)
void scale_cores_kernel(const float* __restrict__ c0, const float* __restrict__ l0,
                        const float* __restrict__ c1, const float* __restrict__ l1,
                        const float* __restrict__ c2, const float* __restrict__ l2,
                        const float* __restrict__ c3, const float* __restrict__ l3,
                        float* __restrict__ ws)
{
    const int gid = blockIdx.x * 256 + threadIdx.x;   // float4 id, 0..51199
    const int d   = gid / 12800;                      // uniform per block
    const int w   = gid - d * 12800;
    const float* cs[4] = {c0, c1, c2, c3};
    const float* ls[4] = {l0, l1, l2, l3};
    const float4 v = reinterpret_cast<const float4*>(cs[d])[w];
    const float4 L = reinterpret_cast<const float4*>(ls[d])[w & 3];
    float4 o;
    o.x = v.x * L.x; o.y = v.y * L.y; o.z = v.z * L.z; o.w = v.w * L.w;
    reinterpret_cast<float4*>(ws)[d * 12800 + w] = o;
}

// ---------------- fallback (lambda applied inline, no workspace) ----------------
DEV void mm16g_lam(const float (&a)[4][16], float (&b)[4][16],
                   const float* __restrict__ m, const float* __restrict__ lam)
{
    const float4* m4 = reinterpret_cast<const float4*>(m);
    float4 lv[4];
#pragma unroll
    for (int q = 0; q < 4; ++q) lv[q] = reinterpret_cast<const float4*>(lam)[q];
#pragma unroll
    for (int nn = 0; nn < 16; ++nn) {
        float mrow[16];
#pragma unroll
        for (int q = 0; q < 4; ++q) {
            float4 v = m4[4 * nn + q];
            v.x *= lv[q].x; v.y *= lv[q].y; v.z *= lv[q].z; v.w *= lv[q].w;
            mrow[4*q+0] = v.x; mrow[4*q+1] = v.y;
            mrow[4*q+2] = v.z; mrow[4*q+3] = v.w;
        }
#pragma unroll
        for (int r = 0; r < 4; ++r) {
            const float av = a[r][nn];
            if (nn == 0) {
#pragma unroll
                for (int k = 0; k < 16; ++k) b[r][k] = av * mrow[k];
            } else {
#pragma unroll
                for (int k = 0; k < 16; ++k) b[r][k] = fmaf(av, mrow[k], b[r][k]);
            }
        }
    }
}

__global__ __launch_bounds__(BLK)
void chain_kernel_fb(const int* __restrict__ idx,
                     const float* __restrict__ c0, const float* __restrict__ l0,
                     const float* __restrict__ c1, const float* __restrict__ l1,
                     const float* __restrict__ c2, const float* __restrict__ l2,
                     const float* __restrict__ c3, const float* __restrict__ l3,
                     float* __restrict__ out, int n)
{
    const int tid  = threadIdx.x;
    const int slot = tid >> 2;
    const int j    = tid & 3;
    const int s    = blockIdx.x * SPB + slot;
    const int sc   = s < n ? s : n - 1;

    const int4 ix = *reinterpret_cast<const int4*>(idx + 4l * sc);

    float a[4][16], b[4][16];
    {
        const float4* src = reinterpret_cast<const float4*>(c0 + 256l * ix.x) + 16 * j;
#pragma unroll
        for (int t = 0; t < 16; ++t) {
            float4 v = src[t];
            const float4 L = reinterpret_cast<const float4*>(l0)[t & 3];
            const int r = t >> 2, c = (t & 3) * 4;
            a[r][c+0] = v.x * L.x; a[r][c+1] = v.y * L.y;
            a[r][c+2] = v.z * L.z; a[r][c+3] = v.w * L.w;
        }
    }

    mm16g_lam(a, b, c1 + 256l * ix.y, l1);
    mm16g_lam(b, a, c2 + 256l * ix.z, l2);

    float4 part = make_float4(0.f, 0.f, 0.f, 0.f);
    const float* base3 = c3 + 256l * ix.w + 4 * j;
#pragma unroll
    for (int nn = 0; nn < 16; ++nn) {
        const float4 v = *reinterpret_cast<const float4*>(base3 + 16 * nn);
        part.x = fmaf(a[0][nn], v.x, part.x);
        part.y = fmaf(a[1][nn], v.y, part.y);
        part.z = fmaf(a[2][nn], v.z, part.z);
        part.w = fmaf(a[3][nn], v.w, part.w);
    }
    const float4 L3 = reinterpret_cast<const float4*>(l3)[j];
    float p = part.x * L3.x + part.y * L3.y + part.z * L3.z + part.w * L3.w;

    p += __shfl_xor(p, 1);
    p += __shfl_xor(p, 2);

    if (s < n && j == 0) out[s] = p;
}

extern "C" void kernel_launch(void* const* d_in, const int* in_sizes, int n_in,
                              void* d_out, int out_size, void* d_ws, size_t ws_size,
                              hipStream_t stream)
{
    const int*   idx = (const int*)  d_in[0];
    const float* c0  = (const float*)d_in[1];
    const float* l0  = (const float*)d_in[2];
    const float* c1  = (const float*)d_in[3];
    const float* l1  = (const float*)d_in[4];
    const float* c2  = (const float*)d_in[5];
    const float* l2  = (const float*)d_in[6];
    const float* c3  = (const float*)d_in[7];
    const float* l3  = (const float*)d_in[8];
    float* out = (float*)d_out;

    const int n    = out_size;                 // 500000
    const int grid = (n + SPB - 1) / SPB;      // 7813 blocks

    const size_t need = 4ull * 200 * 256 * sizeof(float);  // 819,200 B
    if (ws_size >= need) {
        float* W = (float*)d_ws;
        hipLaunchKernelGGL(scale_cores_kernel, dim3(200), dim3(256), 0, stream,
                           c0, l0, c1, l1, c2, l2, c3, l3, W);
        hipLaunchKernelGGL(chain_kernel, dim3(grid), dim3(BLK), 0, stream,
                           idx, W, out, n);
    } else {
        hipLaunchKernelGGL(chain_kernel_fb, dim3(grid), dim3(BLK), 0, stream,
                           idx, c0, l0, c1, l1, c2, l2, c3, l3, out, n);
    }
}

// Round 7
// 88.770 us; speedup vs baseline: 2.2024x; 1.8422x over previous
//
#include <hip/hip_runtime.h>

// BayesTensorRing via MFMA: out[s] = trace(M0'·M1'·M2'·M3'), Md' = core_d[idx_d]·diag(lam_d).
// ranks 16, dims 200, N = 500000.
//
// One sample = one whole wave. Stage 1: T1 = mfma(A=M1'^T, B=M0'^T) = (M0'M1')^T.
// C/D layout (col=l&15,row=4(l>>4)+i) == A layout (row=l&15,k=4(l>>4)+i) of the
// UNtransposed product -> T1 feeds stage 2's A operand directly after f32->f16 cvt.
// Stage 2: T2 = mfma(T1cvt, B=M2') = (M0'M1')·M2'. Trace: per-lane 4-term dot with
// M3'[n][m] (fp32), then 6-step DPP reduce (row_SHR 1/2/4/8 + bcast15/31 -> lane 63).
// (R6 bug: used row_shl, which accumulates to lane 0 of each row while bcast15/31
//  collect lanes 15/31/47 -> lane 63 got garbage. row_shr is the GPUOpen idiom.)
//
// ws layout: W0 f16 M0' row-major @0 (102400B) | W1 f16 M1'^T @102400 |
//            W2 f16 M2'^T @204800 | W3 f32 M3' row-major @307200 (204800B). 512000B total.

typedef _Float16 f16x4 __attribute__((ext_vector_type(4)));
typedef float    f32x4 __attribute__((ext_vector_type(4)));

#define DEV static __device__ __forceinline__

template<int CTRL>
DEV float dppmov(float x)
{
    return __int_as_float(__builtin_amdgcn_update_dpp(
        0, __float_as_int(x), CTRL, 0xF, 0xF, true));
}

__global__ __launch_bounds__(256)
void mfma_chain(const int* __restrict__ idx, const char* __restrict__ wsb,
                float* __restrict__ out, int n)
{
    const _Float16* W0 = (const _Float16*)(wsb);
    const _Float16* W1 = (const _Float16*)(wsb + 102400);
    const _Float16* W2 = (const _Float16*)(wsb + 204800);
    const float*    W3 = (const float*)   (wsb + 307200);

    const int lane = threadIdx.x & 63;
    const int wv   = (blockIdx.x << 2) | (threadIdx.x >> 6);
    const int s0   = __builtin_amdgcn_readfirstlane(wv) << 6;   // uniform wave base
    if (s0 >= n) return;
    const int cnt  = (n - s0 < 64) ? (n - s0) : 64;

    // identical per-lane fragment pattern for all four matrices:
    // element index (l&15)*16 + 4*(l>>4) (+i), one 8B (f16) / 16B (f32) load per lane
    const int hoff = ((lane & 15) << 4) + ((lane >> 4) << 2);

    #define LDI(t)  (*(const int4*)(idx + 4l * (s0 + (((t) < cnt) ? (t) : (cnt - 1)))))
    #define LDA1(i) (*(const f16x4*)(W1 + (i) * 256 + hoff))
    #define LDB0(i) (*(const f16x4*)(W0 + (i) * 256 + hoff))
    #define LDB2(i) (*(const f16x4*)(W2 + (i) * 256 + hoff))
    #define LDM3(i) (*(const f32x4*)(W3 + (i) * 256 + hoff))

    int4  q  = LDI(0);
    f16x4 A1 = LDA1(q.y), B0 = LDB0(q.x), B2 = LDB2(q.z);
    f32x4 M3 = LDM3(q.w);
    int4  qn = LDI(1);

    for (int t = 0; t < cnt; ++t) {
        // prefetch next sample's fragments + idx two ahead
        const f16x4 nA1 = LDA1(qn.y), nB0 = LDB0(qn.x), nB2 = LDB2(qn.z);
        const f32x4 nM3 = LDM3(qn.w);
        const int4  q2  = LDI(t + 2);

        // ---- stage 1: T1 = M1'^T · M0'^T = (M0'·M1')^T
        const f32x4 z = {0.f, 0.f, 0.f, 0.f};
        f32x4 t1 = __builtin_amdgcn_mfma_f32_16x16x16f16(A1, B0, z, 0, 0, 0);

        // f32 -> f16 (RNE casts; compiler packs)
        f16x4 Af;
        Af[0] = (_Float16)t1[0]; Af[1] = (_Float16)t1[1];
        Af[2] = (_Float16)t1[2]; Af[3] = (_Float16)t1[3];

        // ---- stage 2: T2 = (M0'M1') · M2'
        f32x4 t2 = __builtin_amdgcn_mfma_f32_16x16x16f16(Af, B2, z, 0, 0, 0);

        // ---- trace: lane l holds T2[m=4(l>>4)+i][n=l&15]; M3 frag = M3'[n][m_i]
        float p;
        p = t2[0] * M3[0];
        p = fmaf(t2[1], M3[1], p);
        p = fmaf(t2[2], M3[2], p);
        p = fmaf(t2[3], M3[3], p);

        // ---- 64-lane sum (GPUOpen idiom): row_shr 1/2/4/8 -> row sums in lanes
        //      15/31/47/63; row_bcast15 + row_bcast31 funnel total into lane 63
        p += dppmov<0x111>(p);   // row_shr:1
        p += dppmov<0x112>(p);   // row_shr:2
        p += dppmov<0x114>(p);   // row_shr:4
        p += dppmov<0x118>(p);   // row_shr:8
        p += dppmov<0x142>(p);   // row_bcast15
        p += dppmov<0x143>(p);   // row_bcast31

        if (lane == 63) out[s0 + t] = p;

        A1 = nA1; B0 = nB0; B2 = nB2; M3 = nM3; q = qn; qn = q2;
    }
    #undef LDI
    #undef LDA1
    #undef LDB0
    #undef LDB2
    #undef LDM3
}

// Prescale + reformat cores into ws (fp16 W0, W1^T, W2^T; fp32 W3). 400 blocks x 256.
__global__ __launch_bounds__(256)
void prescale_kernel(const float* __restrict__ cr0, const float* __restrict__ lm0,
                     const float* __restrict__ cr1, const float* __restrict__ lm1,
                     const float* __restrict__ cr2, const float* __restrict__ lm2,
                     const float* __restrict__ cr3, const float* __restrict__ lm3,
                     char* __restrict__ wsb)
{
    _Float16* W0 = (_Float16*)(wsb);
    _Float16* W1 = (_Float16*)(wsb + 102400);
    _Float16* W2 = (_Float16*)(wsb + 204800);
    float*    W3 = (float*)   (wsb + 307200);

    const int bx  = blockIdx.x;          // 0..399
    const int d   = bx / 100;            // matrix id (uniform per block)
    const int gid = (bx % 100) * 256 + threadIdx.x;   // 0..25599
    const int i   = gid >> 7;            // slice 0..199
    const int pr  = gid & 127;           // pair id 0..127

    typedef _Float16 h2 __attribute__((ext_vector_type(2)));

    if (d == 0) {
        const int r = pr >> 3, c = (pr & 7) * 2;
        const float2 v = *(const float2*)(cr0 + i * 256 + r * 16 + c);
        h2 o; o[0] = (_Float16)(v.x * lm0[c]); o[1] = (_Float16)(v.y * lm0[c + 1]);
        *(h2*)(W0 + i * 256 + r * 16 + c) = o;
    } else if (d == 1 || d == 2) {
        const float* cp = (d == 1) ? cr1 : cr2;
        const float* lp = (d == 1) ? lm1 : lm2;
        _Float16*    Wt = (d == 1) ? W1 : W2;
        const int c = pr >> 3, r = (pr & 7) * 2;      // store transposed: pos c*16 + r
        const float a = cp[i * 256 + r * 16 + c]       * lp[c];
        const float b = cp[i * 256 + (r + 1) * 16 + c] * lp[c];
        h2 o; o[0] = (_Float16)a; o[1] = (_Float16)b;
        *(h2*)(Wt + i * 256 + c * 16 + r) = o;
    } else {
        const int r = pr >> 3, c = (pr & 7) * 2;
        const float2 v = *(const float2*)(cr3 + i * 256 + r * 16 + c);
        float2 o; o.x = v.x * lm3[c]; o.y = v.y * lm3[c + 1];
        *(float2*)(W3 + i * 256 + r * 16 + c) = o;
    }
}

// ---------------- fallback (no workspace): R5 DPP kernel ----------------
template<int CTRL>
DEV float dppf(float x)
{
    return __int_as_float(__builtin_amdgcn_update_dpp(
        0, __float_as_int(x), CTRL, 0xF, 0xF, true));
}

DEV float getc(const float4& v, int c)
{
    switch (c) { case 0: return v.x; case 1: return v.y; case 2: return v.z; default: return v.w; }
}

DEV void mm16g_lam(const float (&a)[4][16], float (&b)[4][16],
                   const float* __restrict__ m, const float* __restrict__ lam)
{
    const float4* m4 = reinterpret_cast<const float4*>(m);
    float4 lv[4];
#pragma unroll
    for (int q = 0; q < 4; ++q) lv[q] = reinterpret_cast<const float4*>(lam)[q];
#pragma unroll
    for (int nn = 0; nn < 16; ++nn) {
        float mrow[16];
#pragma unroll
        for (int q = 0; q < 4; ++q) {
            float4 v = m4[4 * nn + q];
            v.x *= lv[q].x; v.y *= lv[q].y; v.z *= lv[q].z; v.w *= lv[q].w;
            mrow[4*q+0] = v.x; mrow[4*q+1] = v.y;
            mrow[4*q+2] = v.z; mrow[4*q+3] = v.w;
        }
#pragma unroll
        for (int r = 0; r < 4; ++r) {
            const float av = a[r][nn];
            if (nn == 0) {
#pragma unroll
                for (int k = 0; k < 16; ++k) b[r][k] = av * mrow[k];
            } else {
#pragma unroll
                for (int k = 0; k < 16; ++k) b[r][k] = fmaf(av, mrow[k], b[r][k]);
            }
        }
    }
}

__global__ __launch_bounds__(256)
void chain_kernel_fb(const int* __restrict__ idx,
                     const float* __restrict__ c0, const float* __restrict__ l0,
                     const float* __restrict__ c1, const float* __restrict__ l1,
                     const float* __restrict__ c2, const float* __restrict__ l2,
                     const float* __restrict__ c3, const float* __restrict__ l3,
                     float* __restrict__ out, int n)
{
    const int tid  = threadIdx.x;
    const int slot = tid >> 2;
    const int j    = tid & 3;
    const int s    = blockIdx.x * 64 + slot;
    const int sc   = s < n ? s : n - 1;

    const int4 ix = *reinterpret_cast<const int4*>(idx + 4l * sc);

    float a[4][16], b[4][16];
    {
        const float4* src = reinterpret_cast<const float4*>(c0 + 256l * ix.x) + 16 * j;
#pragma unroll
        for (int t = 0; t < 16; ++t) {
            float4 v = src[t];
            const float4 L = reinterpret_cast<const float4*>(l0)[t & 3];
            const int r = t >> 2, c = (t & 3) * 4;
            a[r][c+0] = v.x * L.x; a[r][c+1] = v.y * L.y;
            a[r][c+2] = v.z * L.z; a[r][c+3] = v.w * L.w;
        }
    }

    mm16g_lam(a, b, c1 + 256l * ix.y, l1);
    mm16g_lam(b, a, c2 + 256l * ix.z, l2);

    float4 part = make_float4(0.f, 0.f, 0.f, 0.f);
    const float* base3 = c3 + 256l * ix.w + 4 * j;
#pragma unroll
    for (int nn = 0; nn < 16; ++nn) {
        const float4 v = *reinterpret_cast<const float4*>(base3 + 16 * nn);
        part.x = fmaf(a[0][nn], v.x, part.x);
        part.y = fmaf(a[1][nn], v.y, part.y);
        part.z = fmaf(a[2][nn], v.z, part.z);
        part.w = fmaf(a[3][nn], v.w, part.w);
    }
    const float4 L3 = reinterpret_cast<const float4*>(l3)[j];
    float p = part.x * L3.x + part.y * L3.y + part.z * L3.z + part.w * L3.w;

    p += __shfl_xor(p, 1);
    p += __shfl_xor(p, 2);

    if (s < n && j == 0) out[s] = p;
}

extern "C" void kernel_launch(void* const* d_in, const int* in_sizes, int n_in,
                              void* d_out, int out_size, void* d_ws, size_t ws_size,
                              hipStream_t stream)
{
    const int*   idx = (const int*)  d_in[0];
    const float* c0  = (const float*)d_in[1];
    const float* l0  = (const float*)d_in[2];
    const float* c1  = (const float*)d_in[3];
    const float* l1  = (const float*)d_in[4];
    const float* c2  = (const float*)d_in[5];
    const float* l2  = (const float*)d_in[6];
    const float* c3  = (const float*)d_in[7];
    const float* l3  = (const float*)d_in[8];
    float* out = (float*)d_out;

    const int n = out_size;                       // 500000

    if (ws_size >= 512000) {
        char* wsb = (char*)d_ws;
        hipLaunchKernelGGL(prescale_kernel, dim3(400), dim3(256), 0, stream,
                           c0, l0, c1, l1, c2, l2, c3, l3, wsb);
        const int waves  = (n + 63) / 64;         // 7813
        const int blocks = (waves + 3) / 4;       // 1954
        hipLaunchKernelGGL(mfma_chain, dim3(blocks), dim3(256), 0, stream,
                           idx, wsb, out, n);
    } else {
        const int grid = (n + 63) / 64;
        hipLaunchKernelGGL(chain_kernel_fb, dim3(grid), dim3(256), 0, stream,
                           idx, c0, l0, c1, l1, c2, l2, c3, l3, out, n);
    }
}

// Round 9
// 74.649 us; speedup vs baseline: 2.6190x; 1.1892x over previous
//
#include <hip/hip_runtime.h>

// BayesTensorRing via MFMA: out[s] = trace(M0'·M1'·M2'·M3'), Md' = core_d[idx_d]·diag(lam_d).
// ranks 16, dims 200, N = 500000. One sample = one wave; 64 samples per wave.
//
// Stage 1: t1 = mfma(A=W1@hoff, B=W0@hoff) = M1'^T·M0'^T = (M0'M1')^T (D-layout of t1
// == A-layout of (M0'M1')). Stage 2: t2 = mfma(cvt(t1), B=W2@hoff) = (M0'M1')·M2'.
// Trace: per-lane 4-term dot with M3'[n][m] (f16), 6-step DPP funnel -> lane 63.
//
// R9 = R8 with the cvt_pkrtz builtin replaced by scalar _Float16 casts (the builtin
// returns __fp16 vec2 which doesn't convert to _Float16 vec2; R7 proved scalar casts
// compile and pack fine).
//
// ws: W0 f16 M0' @0 | W1 f16 M1'^T @102400 | W2 f16 M2'^T @204800 | W3 f16 M3' @307200.
// Total 409600 B.

typedef _Float16 f16x4 __attribute__((ext_vector_type(4)));
typedef _Float16 f16x2 __attribute__((ext_vector_type(2)));
typedef float    f32x4 __attribute__((ext_vector_type(4)));

#define DEV static __device__ __forceinline__

template<int CTRL>
DEV float dppmov(float x)
{
    return __int_as_float(__builtin_amdgcn_update_dpp(
        0, __float_as_int(x), CTRL, 0xF, 0xF, true));
}

struct Frag { f16x4 a1, b0, b2, m3; };

__global__ __launch_bounds__(256)
void mfma_chain(const int* __restrict__ idx, const char* __restrict__ wsb,
                float* __restrict__ out, int n)
{
    const _Float16* W0 = (const _Float16*)(wsb);
    const _Float16* W1 = (const _Float16*)(wsb + 102400);
    const _Float16* W2 = (const _Float16*)(wsb + 204800);
    const _Float16* W3 = (const _Float16*)(wsb + 307200);

    const int lane = threadIdx.x & 63;
    const int wv   = (blockIdx.x << 2) | (threadIdx.x >> 6);
    const int s0   = __builtin_amdgcn_readfirstlane(wv << 6);   // uniform wave base
    if (s0 >= n) return;
    const int cnt  = (n - s0 < 64) ? (n - s0) : 64;

    // identical per-lane fragment element offset for all four matrices:
    // (l&15)*16 + 4*(l>>4), one 8B load per lane covers the 512B slice per wave
    const int hoff = ((lane & 15) << 4) + ((lane >> 4) << 2);

    // uniform (scalar) idx row load, clamped to the tail
    auto LDIDX = [&](int t) -> int4 {
        const int tc = (t < cnt) ? t : (cnt - 1);
        return *(const int4*)(idx + 4l * (s0 + tc));
    };
    // fragment loads: SGPR base (index folded on SALU) + constant per-lane voffset
    auto LDF = [&](int4 q) -> Frag {
        const int i0 = __builtin_amdgcn_readfirstlane(q.x);
        const int i1 = __builtin_amdgcn_readfirstlane(q.y);
        const int i2 = __builtin_amdgcn_readfirstlane(q.z);
        const int i3 = __builtin_amdgcn_readfirstlane(q.w);
        Frag f;
        f.a1 = *(const f16x4*)(W1 + i1 * 256 + hoff);
        f.b0 = *(const f16x4*)(W0 + i0 * 256 + hoff);
        f.b2 = *(const f16x4*)(W2 + i2 * 256 + hoff);
        f.m3 = *(const f16x4*)(W3 + i3 * 256 + hoff);
        return f;
    };
    auto COMPUTE = [&](const Frag& f, int t) {
        const f32x4 z = {0.f, 0.f, 0.f, 0.f};
        f32x4 t1 = __builtin_amdgcn_mfma_f32_16x16x16f16(f.a1, f.b0, z, 0, 0, 0);
        f16x4 Af;
        Af[0] = (_Float16)t1[0]; Af[1] = (_Float16)t1[1];
        Af[2] = (_Float16)t1[2]; Af[3] = (_Float16)t1[3];
        f32x4 t2 = __builtin_amdgcn_mfma_f32_16x16x16f16(Af, f.b2, z, 0, 0, 0);

        float p =       t2[0] * (float)f.m3[0];
        p = fmaf(t2[1], (float)f.m3[1], p);
        p = fmaf(t2[2], (float)f.m3[2], p);
        p = fmaf(t2[3], (float)f.m3[3], p);

        // 64-lane funnel: row_shr 1/2/4/8 -> row sums in lanes 15/31/47/63,
        // then row_bcast15 + row_bcast31 accumulate the total into lane 63
        p += dppmov<0x111>(p);
        p += dppmov<0x112>(p);
        p += dppmov<0x114>(p);
        p += dppmov<0x118>(p);
        p += dppmov<0x142>(p);
        p += dppmov<0x143>(p);

        if (lane == 63) out[s0 + t] = p;
    };

    int4 q1 = LDIDX(1);
    Frag fA = LDF(LDIDX(0));

    int t = 0;
    for (; t + 2 <= cnt; t += 2) {
        Frag fB = LDF(q1);              // issue loads for sample t+1
        const int4 q2 = LDIDX(t + 2);   // scalar prefetch (clamped)
        const int4 q3 = LDIDX(t + 3);
        COMPUTE(fA, t);                 // consume sample t
        fA = LDF(q2);                   // issue loads for sample t+2
        q1 = q3;
        COMPUTE(fB, t + 1);             // consume sample t+1
    }
    if (t < cnt) COMPUTE(fA, t);
}

// Prescale + reformat cores into ws (all f16: W0, W1^T, W2^T, W3). 400 blocks x 256.
__global__ __launch_bounds__(256)
void prescale_kernel(const float* __restrict__ cr0, const float* __restrict__ lm0,
                     const float* __restrict__ cr1, const float* __restrict__ lm1,
                     const float* __restrict__ cr2, const float* __restrict__ lm2,
                     const float* __restrict__ cr3, const float* __restrict__ lm3,
                     char* __restrict__ wsb)
{
    _Float16* W0 = (_Float16*)(wsb);
    _Float16* W1 = (_Float16*)(wsb + 102400);
    _Float16* W2 = (_Float16*)(wsb + 204800);
    _Float16* W3 = (_Float16*)(wsb + 307200);

    const int bx  = blockIdx.x;          // 0..399
    const int d   = bx / 100;            // matrix id (uniform per block)
    const int gid = (bx % 100) * 256 + threadIdx.x;   // 0..25599
    const int i   = gid >> 7;            // slice 0..199
    const int pr  = gid & 127;           // pair id 0..127

    if (d == 0) {
        const int r = pr >> 3, c = (pr & 7) * 2;
        const float2 v = *(const float2*)(cr0 + i * 256 + r * 16 + c);
        f16x2 o; o[0] = (_Float16)(v.x * lm0[c]); o[1] = (_Float16)(v.y * lm0[c + 1]);
        *(f16x2*)(W0 + i * 256 + r * 16 + c) = o;
    } else if (d == 1 || d == 2) {
        const float* cp = (d == 1) ? cr1 : cr2;
        const float* lp = (d == 1) ? lm1 : lm2;
        _Float16*    Wt = (d == 1) ? W1 : W2;
        const int c = pr >> 3, r = (pr & 7) * 2;      // store transposed: pos c*16 + r
        const float a = cp[i * 256 + r * 16 + c]       * lp[c];
        const float b = cp[i * 256 + (r + 1) * 16 + c] * lp[c];
        f16x2 o; o[0] = (_Float16)a; o[1] = (_Float16)b;
        *(f16x2*)(Wt + i * 256 + c * 16 + r) = o;
    } else {
        const int r = pr >> 3, c = (pr & 7) * 2;
        const float2 v = *(const float2*)(cr3 + i * 256 + r * 16 + c);
        f16x2 o; o[0] = (_Float16)(v.x * lm3[c]); o[1] = (_Float16)(v.y * lm3[c + 1]);
        *(f16x2*)(W3 + i * 256 + r * 16 + c) = o;
    }
}

// ---------------- fallback (no workspace): R5 DPP vector kernel ----------------
template<int CTRL>
DEV float dppf(float x)
{
    return __int_as_float(__builtin_amdgcn_update_dpp(
        0, __float_as_int(x), CTRL, 0xF, 0xF, true));
}

DEV float getc(const float4& v, int c)
{
    switch (c) { case 0: return v.x; case 1: return v.y; case 2: return v.z; default: return v.w; }
}

DEV void mm16g_lam(const float (&a)[4][16], float (&b)[4][16],
                   const float* __restrict__ m, const float* __restrict__ lam)
{
    const float4* m4 = reinterpret_cast<const float4*>(m);
    float4 lv[4];
#pragma unroll
    for (int q = 0; q < 4; ++q) lv[q] = reinterpret_cast<const float4*>(lam)[q];
#pragma unroll
    for (int nn = 0; nn < 16; ++nn) {
        float mrow[16];
#pragma unroll
        for (int q = 0; q < 4; ++q) {
            float4 v = m4[4 * nn + q];
            v.x *= lv[q].x; v.y *= lv[q].y; v.z *= lv[q].z; v.w *= lv[q].w;
            mrow[4*q+0] = v.x; mrow[4*q+1] = v.y;
            mrow[4*q+2] = v.z; mrow[4*q+3] = v.w;
        }
#pragma unroll
        for (int r = 0; r < 4; ++r) {
            const float av = a[r][nn];
            if (nn == 0) {
#pragma unroll
                for (int k = 0; k < 16; ++k) b[r][k] = av * mrow[k];
            } else {
#pragma unroll
                for (int k = 0; k < 16; ++k) b[r][k] = fmaf(av, mrow[k], b[r][k]);
            }
        }
    }
}

__global__ __launch_bounds__(256)
void chain_kernel_fb(const int* __restrict__ idx,
                     const float* __restrict__ c0, const float* __restrict__ l0,
                     const float* __restrict__ c1, const float* __restrict__ l1,
                     const float* __restrict__ c2, const float* __restrict__ l2,
                     const float* __restrict__ c3, const float* __restrict__ l3,
                     float* __restrict__ out, int n)
{
    const int tid  = threadIdx.x;
    const int slot = tid >> 2;
    const int j    = tid & 3;
    const int s    = blockIdx.x * 64 + slot;
    const int sc   = s < n ? s : n - 1;

    const int4 ix = *reinterpret_cast<const int4*>(idx + 4l * sc);

    float a[4][16], b[4][16];
    {
        const float4* src = reinterpret_cast<const float4*>(c0 + 256l * ix.x) + 16 * j;
#pragma unroll
        for (int t = 0; t < 16; ++t) {
            float4 v = src[t];
            const float4 L = reinterpret_cast<const float4*>(l0)[t & 3];
            const int r = t >> 2, c = (t & 3) * 4;
            a[r][c+0] = v.x * L.x; a[r][c+1] = v.y * L.y;
            a[r][c+2] = v.z * L.z; a[r][c+3] = v.w * L.w;
        }
    }

    mm16g_lam(a, b, c1 + 256l * ix.y, l1);
    mm16g_lam(b, a, c2 + 256l * ix.z, l2);

    float4 part = make_float4(0.f, 0.f, 0.f, 0.f);
    const float* base3 = c3 + 256l * ix.w + 4 * j;
#pragma unroll
    for (int nn = 0; nn < 16; ++nn) {
        const float4 v = *reinterpret_cast<const float4*>(base3 + 16 * nn);
        part.x = fmaf(a[0][nn], v.x, part.x);
        part.y = fmaf(a[1][nn], v.y, part.y);
        part.z = fmaf(a[2][nn], v.z, part.z);
        part.w = fmaf(a[3][nn], v.w, part.w);
    }
    const float4 L3 = reinterpret_cast<const float4*>(l3)[j];
    float p = part.x * L3.x + part.y * L3.y + part.z * L3.z + part.w * L3.w;

    p += __shfl_xor(p, 1);
    p += __shfl_xor(p, 2);

    if (s < n && j == 0) out[s] = p;
}

extern "C" void kernel_launch(void* const* d_in, const int* in_sizes, int n_in,
                              void* d_out, int out_size, void* d_ws, size_t ws_size,
                              hipStream_t stream)
{
    const int*   idx = (const int*)  d_in[0];
    const float* c0  = (const float*)d_in[1];
    const float* l0  = (const float*)d_in[2];
    const float* c1  = (const float*)d_in[3];
    const float* l1  = (const float*)d_in[4];
    const float* c2  = (const float*)d_in[5];
    const float* l2  = (const float*)d_in[6];
    const float* c3  = (const float*)d_in[7];
    const float* l3  = (const float*)d_in[8];
    float* out = (float*)d_out;

    const int n = out_size;                       // 500000

    if (ws_size >= 409600) {
        char* wsb = (char*)d_ws;
        hipLaunchKernelGGL(prescale_kernel, dim3(400), dim3(256), 0, stream,
                           c0, l0, c1, l1, c2, l2, c3, l3, wsb);
        const int waves  = (n + 63) / 64;         // 7813
        const int blocks = (waves + 3) / 4;       // 1954
        hipLaunchKernelGGL(mfma_chain, dim3(blocks), dim3(256), 0, stream,
                           idx, wsb, out, n);
    } else {
        const int grid = (n + 63) / 64;
        hipLaunchKernelGGL(chain_kernel_fb, dim3(grid), dim3(256), 0, stream,
                           idx, c0, l0, c1, l1, c2, l2, c3, l3, out, n);
    }
}